// Round 11
// baseline (289.533 us; speedup 1.0000x reference)
//
#include <hip/hip_runtime.h>
#include <hip/hip_fp16.h>

#define N_NODES 100000
#define N_EDGES 1200000
#define D 64
#define N_CLASSES 16
#define NG8  (N_NODES / 8)
#define GRID 2048
#define NXCD 8
#define DRANGE ((N_NODES + NXCD - 1) / NXCD)   // 12500
#define ESRC_CAP 1900032           // >= E + 7N (pad-8)
#define SENTINEL N_NODES           // index of the all-zero h row
#define NB_CVT 6250                // 100000*64/4 float4 elems / 256

typedef _Float16 f16x8 __attribute__((ext_vector_type(8)));
typedef float    f32x4 __attribute__((ext_vector_type(4)));
typedef int      i32x4 __attribute__((ext_vector_type(4)));
typedef unsigned u32x2 __attribute__((ext_vector_type(2)));

// ======================= CSR build kernels ================================

// XCD-range-partitioned histogram; dst read is nontemporal so the streamed
// 77MB does not evict the 50KB cnt window from the local L2.
__global__ __launch_bounds__(256) void hist_kernel(const int* __restrict__ dst,
                                                   int* __restrict__ cnt) {
    int g = blockIdx.x & (NXCD - 1);
    int lo = g * DRANGE, hi = lo + DRANGE;
    int t = (blockIdx.x >> 3) * 256 + threadIdx.x;
    const int NCH = N_EDGES / 4;
    const int STRIDE = (GRID / NXCD) * 256;
    for (int c = t; c < NCH; c += STRIDE) {
        i32x4 d4 = __builtin_nontemporal_load((const i32x4*)dst + c);
        if (d4.x >= lo && d4.x < hi) atomicAdd(&cnt[d4.x], 1);
        if (d4.y >= lo && d4.y < hi) atomicAdd(&cnt[d4.y], 1);
        if (d4.z >= lo && d4.z < hi) atomicAdd(&cnt[d4.z], 1);
        if (d4.w >= lo && d4.w < hi) atomicAdd(&cnt[d4.w], 1);
    }
}

// Exclusive scan over PADDED degrees: pad_deg = ceil(deg/8)*8.
__global__ void scan_block_kernel(const int* __restrict__ cnt,
                                  int* __restrict__ ofs,
                                  int* __restrict__ partial) {
    __shared__ int s[256];
    int tid = threadIdx.x;
    int i = blockIdx.x * 256 + tid;
    int v = (i < N_NODES) ? ((cnt[i] + 7) & ~7) : 0;
    s[tid] = v;
    __syncthreads();
    for (int d = 1; d < 256; d <<= 1) {
        int t = (tid >= d) ? s[tid - d] : 0;
        __syncthreads();
        s[tid] += t;
        __syncthreads();
    }
    if (i < N_NODES) ofs[i] = s[tid] - v;
    if (tid == 255) partial[blockIdx.x] = s[255];
}

__global__ void scan_partials_kernel(int* __restrict__ partial, int nb) {
    __shared__ int s[512];
    int tid = threadIdx.x;
    int v = (tid < nb) ? partial[tid] : 0;
    s[tid] = v;
    __syncthreads();
    for (int d = 1; d < 512; d <<= 1) {
        int t = (tid >= d) ? s[tid - d] : 0;
        __syncthreads();
        s[tid] += t;
        __syncthreads();
    }
    if (tid < nb) partial[tid] = s[tid] - v;
}

// Adds block prefix AND writes the <=7 sentinel pads of each node's segment.
__global__ void scan_add_kernel(int* __restrict__ ofs,
                                const int* __restrict__ partial,
                                const int* __restrict__ cnt,
                                int* __restrict__ esrc) {
    int i = blockIdx.x * 256 + threadIdx.x;
    if (i < N_NODES) {
        int o = ofs[i] + partial[blockIdx.x];
        ofs[i] = o;
        int c = cnt[i], p = (c + 7) & ~7;
        for (int j = c; j < p; ++j) esrc[o + j] = SENTINEL;
        if (i == N_NODES - 1) ofs[N_NODES] = o + p;
    }
}

// XCD-range-partitioned scatter (down-cursor on cnt); src/dst reads
// nontemporal -> esrc slice (~950KB) and cnt stay L2-resident, killing the
// write-allocate churn (round-10: 38MB fetch + 54MB write for 7.6MB data).
__global__ __launch_bounds__(256) void scatter_edges_kernel(
        const int* __restrict__ src,
        const int* __restrict__ dst,
        const int* __restrict__ ofs,
        int* __restrict__ cnt,
        int* __restrict__ esrc) {
    int g = blockIdx.x & (NXCD - 1);
    int lo = g * DRANGE, hi = lo + DRANGE;
    int t = (blockIdx.x >> 3) * 256 + threadIdx.x;
    const int NCH = N_EDGES / 4;
    const int STRIDE = (GRID / NXCD) * 256;
    for (int c = t; c < NCH; c += STRIDE) {
        i32x4 s4 = __builtin_nontemporal_load((const i32x4*)src + c);
        i32x4 d4 = __builtin_nontemporal_load((const i32x4*)dst + c);
        if (d4.x >= lo && d4.x < hi) esrc[ofs[d4.x] + atomicSub(&cnt[d4.x], 1) - 1] = s4.x;
        if (d4.y >= lo && d4.y < hi) esrc[ofs[d4.y] + atomicSub(&cnt[d4.y], 1) - 1] = s4.y;
        if (d4.z >= lo && d4.z < hi) esrc[ofs[d4.z] + atomicSub(&cnt[d4.z], 1) - 1] = s4.z;
        if (d4.w >= lo && d4.w < hi) esrc[ofs[d4.w] + atomicSub(&cnt[d4.w], 1) - 1] = s4.w;
    }
}

// ====== Prep: x->fp16, W0..W2->fp16, zero sentinel rows (one kernel) ======
__global__ void prep_kernel(const float* __restrict__ x,
                            const float* __restrict__ W0,
                            const float* __restrict__ W1,
                            const float* __restrict__ W2,
                            __half* __restrict__ x16,
                            __half* __restrict__ w16,   // [3][4096]
                            __half* __restrict__ bufA,
                            __half* __restrict__ bufB) {
    int b = blockIdx.x;
    if (b < NB_CVT) {
        int i = b * 256 + threadIdx.x;
        f32x4 v = __builtin_nontemporal_load((const f32x4*)x + i);
        __half2 h01 = __floats2half2_rn(v.x, v.y);
        __half2 h23 = __floats2half2_rn(v.z, v.w);
        u32x2 ov = { *(unsigned*)&h01, *(unsigned*)&h23 };
        __builtin_nontemporal_store(ov, (u32x2*)x16 + i);
    } else if (b < NB_CVT + 3) {
        int l = b - NB_CVT;
        const float* W = (l == 0) ? W0 : (l == 1) ? W1 : W2;
        for (int j = threadIdx.x; j < D * D; j += 256)
            w16[l * D * D + j] = __float2half(W[j]);
    } else {
        int tid = threadIdx.x;
        if (tid < 96) {
            __half* p = (tid < 32) ? x16 : (tid < 64) ? bufA : bufB;
            ((unsigned int*)(p + SENTINEL * D))[tid & 31] = 0u;
        }
    }
}

// ================= Gather: S[n] = h[n] + sum_neighbors h ==================
// Pure gather, no LDS, no barrier. Quarter-wave: 16 lanes/node, lane owns 4
// channels (uint2). Segments padded to 8 with sentinel (zero row).
// esrc reads + S writes nontemporal: the random h rows get the whole L2.
__global__ __launch_bounds__(256) void gather_kernel(
        const __half* __restrict__ h_in,
        const int* __restrict__ ofs,
        const int* __restrict__ esrc,
        __half* __restrict__ s_out) {
    int w = threadIdx.x >> 6, lane = threadIdx.x & 63;
    int q = lane >> 4;
    int c4 = lane & 15;
    int n = blockIdx.x * 16 + w * 4 + q;   // grid 6250 -> n < 100000 exact
    const uint2* hp = (const uint2*)h_in;

    uint2 self = hp[n * 16 + c4];
    float2 sl = __half22float2(*(const __half2*)&self.x);
    float2 sh = __half22float2(*(const __half2*)&self.y);
    float a0 = sl.x, a1 = sl.y, a2 = sh.x, a3 = sh.y;

    int k = ofs[n], end = ofs[n + 1];
    for (; k < end; k += 8) {
        i32x4 i0 = __builtin_nontemporal_load((const i32x4*)(esrc + k));
        i32x4 i1 = __builtin_nontemporal_load((const i32x4*)(esrc + k + 4));
        uint2 r0 = hp[i0.x * 16 + c4];
        uint2 r1 = hp[i0.y * 16 + c4];
        uint2 r2 = hp[i0.z * 16 + c4];
        uint2 r3 = hp[i0.w * 16 + c4];
        uint2 r4 = hp[i1.x * 16 + c4];
        uint2 r5 = hp[i1.y * 16 + c4];
        uint2 r6 = hp[i1.z * 16 + c4];
        uint2 r7 = hp[i1.w * 16 + c4];
#define ACC(R) { float2 lo = __half22float2(*(const __half2*)&R.x); \
                 float2 hi = __half22float2(*(const __half2*)&R.y); \
                 a0 += lo.x; a1 += lo.y; a2 += hi.x; a3 += hi.y; }
        ACC(r0) ACC(r1) ACC(r2) ACC(r3) ACC(r4) ACC(r5) ACC(r6) ACC(r7)
#undef ACC
    }
    __half2 h01 = __floats2half2_rn(a0, a1);
    __half2 h23 = __floats2half2_rn(a2, a3);
    u32x2 ov = { *(unsigned*)&h01, *(unsigned*)&h23 };
    __builtin_nontemporal_store(ov, (u32x2*)s_out + n * 16 + c4);
}

// ================= MLP: h' = relu(S @ W) via MFMA =========================
// Wave = 16-node tile. W lives in 8 B-fragments (32 VGPR), loaded once.
// A: lane holds S[t*16 + (lane&15)][kt*32 + (lane>>4)*8 + j]
// B: lane holds W[kt*32 + (lane>>4)*8 + j][ct*16 + (lane&15)]
// D: row=(lane>>4)*4+r, col=ct*16+(lane&15)   [m89-verified layout]
__global__ __launch_bounds__(256) void mlp_kernel(
        const __half* __restrict__ S,
        const __half* __restrict__ W16,   // [64][64] fp16 [in][out]
        __half* __restrict__ h_out) {
    int w = threadIdx.x >> 6, lane = threadIdx.x & 63;
    int m = lane & 15;
    int kg = lane >> 4;
    const _Float16* Wp = (const _Float16*)W16;
    f16x8 bf[4][2];
#pragma unroll
    for (int ct = 0; ct < 4; ++ct)
#pragma unroll
        for (int kt = 0; kt < 2; ++kt)
#pragma unroll
            for (int j = 0; j < 8; ++j)
                bf[ct][kt][j] = Wp[(kt * 32 + kg * 8 + j) * D + ct * 16 + m];

    int t = blockIdx.x * 4 + w;
    if (t >= N_NODES / 16) return;
    const _Float16* Sp = (const _Float16*)S;
    int row = t * 16 + m;
    f16x8 a0 = __builtin_nontemporal_load((const f16x8*)(Sp + row * D + kg * 8));
    f16x8 a1 = __builtin_nontemporal_load((const f16x8*)(Sp + row * D + 32 + kg * 8));
    f32x4 c[4];
#pragma unroll
    for (int ct = 0; ct < 4; ++ct) {
        f32x4 z = {0.f, 0.f, 0.f, 0.f};
        z = __builtin_amdgcn_mfma_f32_16x16x32_f16(a0, bf[ct][0], z, 0, 0, 0);
        z = __builtin_amdgcn_mfma_f32_16x16x32_f16(a1, bf[ct][1], z, 0, 0, 0);
        c[ct] = z;
    }
#pragma unroll
    for (int ct = 0; ct < 4; ++ct)
#pragma unroll
        for (int r = 0; r < 4; ++r) {
            _Float16 hv = (_Float16)fmaxf(c[ct][r], 0.f);
            __builtin_nontemporal_store(hv,
                (_Float16*)h_out + (t * 16 + kg * 4 + r) * D + ct * 16 + m);
        }
}

// ============ Final: L2-normalize + 64->16 linear (fp16 in) ===============
__global__ __launch_bounds__(256) void final_kernel(
        const __half* __restrict__ h,
        const float* __restrict__ W_out,
        const float* __restrict__ b_out,
        float* __restrict__ out,    // [N,16]
        float* __restrict__ feat) { // [N,64]
    __shared__ float Wo[D][N_CLASSES];
    __shared__ float fs[4][2][D];
    int tid = threadIdx.x;
    for (int k = tid; k < D * N_CLASSES; k += 256)
        Wo[k >> 4][k & 15] = W_out[k];
    __syncthreads();
    int w = tid >> 6;
    int lane = tid & 63;
    int hh = lane >> 5;
    int c2 = lane & 31;
    const __half2* hp = (const __half2*)h;
    float bias = b_out[lane & 15];

    for (int g = blockIdx.x; g < NG8; g += GRID) {
        int n = g * 8 + w * 2 + hh;
        float2 v = __half22float2(hp[n * 32 + c2]);
        float ss = v.x * v.x + v.y * v.y;
#pragma unroll
        for (int off = 16; off; off >>= 1)
            ss += __shfl_xor(ss, off);
        float rinv = 1.f / fmaxf(sqrtf(ss), 1e-12f);
        float f0 = v.x * rinv, f1 = v.y * rinv;
        float2 fv = make_float2(f0, f1);
        __builtin_nontemporal_store(fv.x, &feat[n * D + 2 * c2]);
        __builtin_nontemporal_store(fv.y, &feat[n * D + 2 * c2 + 1]);
        fs[w][hh][2 * c2 + 0] = f0;
        fs[w][hh][2 * c2 + 1] = f1;
        if (c2 < N_CLASSES) {
            float acc = bias;
#pragma unroll
            for (int i = 0; i < D; ++i)
                acc = fmaf(fs[w][hh][i], Wo[i][c2], acc);
            __builtin_nontemporal_store(acc, &out[n * N_CLASSES + c2]);
        }
    }
}

// ==========================================================================
extern "C" void kernel_launch(void* const* d_in, const int* in_sizes, int n_in,
                              void* d_out, int out_size, void* d_ws, size_t ws_size,
                              hipStream_t stream) {
    const float* x     = (const float*)d_in[0];
    const int*   src   = (const int*)d_in[1];
    const int*   dst   = (const int*)d_in[2];
    const float* W0    = (const float*)d_in[3];
    const float* W1    = (const float*)d_in[4];
    const float* W2    = (const float*)d_in[5];
    const float* W_out = (const float*)d_in[6];
    const float* b_out = (const float*)d_in[7];

    float* out  = (float*)d_out;
    float* feat = (float*)d_out + (size_t)N_NODES * N_CLASSES;

    const int NB_NODE = (N_NODES + 255) / 256;       // 391
    const int NB_MLP  = (N_NODES / 16 + 3) / 4;      // 1563

    // ws layout; h buffers have N_NODES+1 rows (sentinel zero row)
    size_t off = 0;
    auto alloc = [&](size_t bytes) { size_t o = off; off = (off + bytes + 255) & ~(size_t)255; return o; };
    size_t o_cnt     = alloc((size_t)N_NODES * 4);
    size_t o_partial = alloc(512 * 4);
    size_t o_ofs     = alloc(((size_t)N_NODES + 1) * 4);
    size_t o_esrc    = alloc((size_t)ESRC_CAP * 4);
    size_t o_w16     = alloc((size_t)3 * D * D * 2);
    size_t o_X       = alloc((size_t)(N_NODES + 1) * D * 2);
    size_t o_A       = alloc((size_t)(N_NODES + 1) * D * 2);
    size_t o_B       = alloc((size_t)(N_NODES + 1) * D * 2);

    char* w8 = (char*)d_ws;
    int*    cnt     = (int*)(w8 + o_cnt);
    int*    partial = (int*)(w8 + o_partial);
    int*    ofs     = (int*)(w8 + o_ofs);
    int*    esrc    = (int*)(w8 + o_esrc);
    __half* w16     = (__half*)(w8 + o_w16);
    __half* X       = (__half*)(w8 + o_X);
    __half* A       = (__half*)(w8 + o_A);
    __half* B       = (__half*)(w8 + o_B);

    // --- padded CSR build ---
    hipMemsetAsync(cnt, 0, (size_t)N_NODES * 4, stream);
    hist_kernel<<<GRID, 256, 0, stream>>>(dst, cnt);
    scan_block_kernel<<<NB_NODE, 256, 0, stream>>>(cnt, ofs, partial);
    scan_partials_kernel<<<1, 512, 0, stream>>>(partial, NB_NODE);
    scan_add_kernel<<<NB_NODE, 256, 0, stream>>>(ofs, partial, cnt, esrc);
    scatter_edges_kernel<<<GRID, 256, 0, stream>>>(src, dst, ofs, cnt, esrc);

    // --- prep: x->fp16, W->fp16, zero sentinel rows ---
    prep_kernel<<<NB_CVT + 4, 256, 0, stream>>>(x, W0, W1, W2, X, w16, A, B);

    // --- 3 layers: gather then MFMA MLP; buffers rotate X->A->B ---
    gather_kernel<<<N_NODES / 16, 256, 0, stream>>>(X, ofs, esrc, A);       // S1=A
    mlp_kernel<<<NB_MLP, 256, 0, stream>>>(A, w16 + 0 * D * D, B);          // h1=B
    gather_kernel<<<N_NODES / 16, 256, 0, stream>>>(B, ofs, esrc, X);       // S2=X
    mlp_kernel<<<NB_MLP, 256, 0, stream>>>(X, w16 + 1 * D * D, A);          // h2=A
    gather_kernel<<<N_NODES / 16, 256, 0, stream>>>(A, ofs, esrc, B);       // S3=B
    mlp_kernel<<<NB_MLP, 256, 0, stream>>>(B, w16 + 2 * D * D, X);          // h3=X

    final_kernel<<<GRID, 256, 0, stream>>>(X, W_out, b_out, out, feat);
}

// Round 12
// 273.758 us; speedup vs baseline: 1.0576x; 1.0576x over previous
//
#include <hip/hip_runtime.h>
#include <hip/hip_fp16.h>

#define N_NODES 100000
#define N_EDGES 1200000
#define D 64
#define N_CLASSES 16
#define NG8  (N_NODES / 8)
#define GRID 2048
#define NXCD 8
#define DRANGE ((N_NODES + NXCD - 1) / NXCD)   // 12500
#define ESRC_CAP 1900032           // >= E + 7N (pad-8)
#define SENTINEL N_NODES           // index of the all-zero h row
#define NB_CVT 6250                // 100000*64/4 float4 elems / 256
#define BCAP 160000                // per-bucket capacity (exp 150000, 27 sigma)

typedef _Float16 f16x8 __attribute__((ext_vector_type(8)));
typedef float    f32x4 __attribute__((ext_vector_type(4)));

// ======================= CSR build kernels ================================

// --- Pass 1: partition edges into 8 dst-range buckets (LDS-binned) --------
// Block handles 1024 edges; ranks via LDS atomics; one global cursor atomic
// per bucket per block; flush is segment-coalesced.
__global__ __launch_bounds__(256) void bucket_kernel(
        const int* __restrict__ src,
        const int* __restrict__ dst,
        int* __restrict__ bcur,          // [8]
        int* __restrict__ bsrc,          // [8][BCAP]
        int* __restrict__ bdst) {        // [8][BCAP]
    __shared__ int lsrc[1024], ldst[1024];
    __shared__ int lcnt[8], lofs[9], gbase[8];
    int tid = threadIdx.x;
    if (tid < 8) lcnt[tid] = 0;
    __syncthreads();

    int c = blockIdx.x * 256 + tid;      // int4 index
    int4 s4, d4;
    int bn[4] = {0, 0, 0, 0}, rk[4] = {0, 0, 0, 0};
    bool valid = c < N_EDGES / 4;
    if (valid) {
        s4 = ((const int4*)src)[c];
        d4 = ((const int4*)dst)[c];
        int dd[4] = {d4.x, d4.y, d4.z, d4.w};
#pragma unroll
        for (int j = 0; j < 4; ++j) {
            bn[j] = dd[j] / DRANGE;
            rk[j] = atomicAdd(&lcnt[bn[j]], 1);
        }
    }
    __syncthreads();
    if (tid == 0) {
        int acc = 0;
#pragma unroll
        for (int b = 0; b < 8; ++b) { lofs[b] = acc; acc += lcnt[b]; }
        lofs[8] = acc;
    }
    if (tid < 8) gbase[tid] = atomicAdd(&bcur[tid], lcnt[tid]);
    __syncthreads();
    if (valid) {
        int ss[4] = {s4.x, s4.y, s4.z, s4.w};
        int dd[4] = {d4.x, d4.y, d4.z, d4.w};
#pragma unroll
        for (int j = 0; j < 4; ++j) {
            int p = lofs[bn[j]] + rk[j];
            lsrc[p] = ss[j];
            ldst[p] = dd[j];
        }
    }
    __syncthreads();
    int total = lofs[8];
    for (int i = tid; i < total; i += 256) {
        int b = 0;
#pragma unroll
        for (int t = 0; t < 7; ++t) b += (i >= lofs[t + 1]);
        int gpos = b * BCAP + gbase[b] + (i - lofs[b]);
        bsrc[gpos] = lsrc[i];
        bdst[gpos] = ldst[i];
    }
}

// --- Pass 2: histogram from own bucket (XCD-local) ------------------------
__global__ __launch_bounds__(256) void hist_bucket_kernel(
        const int* __restrict__ bcur,
        const int* __restrict__ bdst,
        int* __restrict__ cnt) {
    int g = blockIdx.x & (NXCD - 1);
    int nb = bcur[g];
    const int* bd = bdst + g * BCAP;
    const int STRIDE = (GRID / NXCD) * 256;
    for (int i = (blockIdx.x >> 3) * 256 + threadIdx.x; i < nb; i += STRIDE)
        atomicAdd(&cnt[bd[i]], 1);
}

// Exclusive scan over PADDED degrees: pad_deg = ceil(deg/8)*8.
__global__ void scan_block_kernel(const int* __restrict__ cnt,
                                  int* __restrict__ ofs,
                                  int* __restrict__ partial) {
    __shared__ int s[256];
    int tid = threadIdx.x;
    int i = blockIdx.x * 256 + tid;
    int v = (i < N_NODES) ? ((cnt[i] + 7) & ~7) : 0;
    s[tid] = v;
    __syncthreads();
    for (int d = 1; d < 256; d <<= 1) {
        int t = (tid >= d) ? s[tid - d] : 0;
        __syncthreads();
        s[tid] += t;
        __syncthreads();
    }
    if (i < N_NODES) ofs[i] = s[tid] - v;
    if (tid == 255) partial[blockIdx.x] = s[255];
}

__global__ void scan_partials_kernel(int* __restrict__ partial, int nb) {
    __shared__ int s[512];
    int tid = threadIdx.x;
    int v = (tid < nb) ? partial[tid] : 0;
    s[tid] = v;
    __syncthreads();
    for (int d = 1; d < 512; d <<= 1) {
        int t = (tid >= d) ? s[tid - d] : 0;
        __syncthreads();
        s[tid] += t;
        __syncthreads();
    }
    if (tid < nb) partial[tid] = s[tid] - v;
}

// Adds block prefix AND writes the <=7 sentinel pads of each node's segment.
__global__ void scan_add_kernel(int* __restrict__ ofs,
                                const int* __restrict__ partial,
                                const int* __restrict__ cnt,
                                int* __restrict__ esrc) {
    int i = blockIdx.x * 256 + threadIdx.x;
    if (i < N_NODES) {
        int o = ofs[i] + partial[blockIdx.x];
        ofs[i] = o;
        int c = cnt[i], p = (c + 7) & ~7;
        for (int j = c; j < p; ++j) esrc[o + j] = SENTINEL;
        if (i == N_NODES - 1) ofs[N_NODES] = o + p;
    }
}

// --- Pass 3: scatter from own bucket (all traffic XCD-local) --------------
__global__ __launch_bounds__(256) void scatter_bucket_kernel(
        const int* __restrict__ bcur,
        const int* __restrict__ bsrc,
        const int* __restrict__ bdst,
        const int* __restrict__ ofs,
        int* __restrict__ cnt,
        int* __restrict__ esrc) {
    int g = blockIdx.x & (NXCD - 1);
    int nb = bcur[g];
    const int* bs = bsrc + g * BCAP;
    const int* bd = bdst + g * BCAP;
    const int STRIDE = (GRID / NXCD) * 256;
    for (int i = (blockIdx.x >> 3) * 256 + threadIdx.x; i < nb; i += STRIDE) {
        int d = bd[i];
        esrc[ofs[d] + atomicSub(&cnt[d], 1) - 1] = bs[i];
    }
}

// --- Fallback (round-10 path, if ws too small for buckets) ----------------
__global__ __launch_bounds__(256) void hist_kernel(const int* __restrict__ dst,
                                                   int* __restrict__ cnt) {
    int g = blockIdx.x & (NXCD - 1);
    int lo = g * DRANGE, hi = lo + DRANGE;
    int t = (blockIdx.x >> 3) * 256 + threadIdx.x;
    const int NCH = N_EDGES / 4;
    const int STRIDE = (GRID / NXCD) * 256;
    for (int c = t; c < NCH; c += STRIDE) {
        int4 d4 = ((const int4*)dst)[c];
        if (d4.x >= lo && d4.x < hi) atomicAdd(&cnt[d4.x], 1);
        if (d4.y >= lo && d4.y < hi) atomicAdd(&cnt[d4.y], 1);
        if (d4.z >= lo && d4.z < hi) atomicAdd(&cnt[d4.z], 1);
        if (d4.w >= lo && d4.w < hi) atomicAdd(&cnt[d4.w], 1);
    }
}

__global__ __launch_bounds__(256) void scatter_edges_kernel(
        const int* __restrict__ src,
        const int* __restrict__ dst,
        const int* __restrict__ ofs,
        int* __restrict__ cnt,
        int* __restrict__ esrc) {
    int g = blockIdx.x & (NXCD - 1);
    int lo = g * DRANGE, hi = lo + DRANGE;
    int t = (blockIdx.x >> 3) * 256 + threadIdx.x;
    const int NCH = N_EDGES / 4;
    const int STRIDE = (GRID / NXCD) * 256;
    for (int c = t; c < NCH; c += STRIDE) {
        int4 s4 = ((const int4*)src)[c];
        int4 d4 = ((const int4*)dst)[c];
        if (d4.x >= lo && d4.x < hi) esrc[ofs[d4.x] + atomicSub(&cnt[d4.x], 1) - 1] = s4.x;
        if (d4.y >= lo && d4.y < hi) esrc[ofs[d4.y] + atomicSub(&cnt[d4.y], 1) - 1] = s4.y;
        if (d4.z >= lo && d4.z < hi) esrc[ofs[d4.z] + atomicSub(&cnt[d4.z], 1) - 1] = s4.z;
        if (d4.w >= lo && d4.w < hi) esrc[ofs[d4.w] + atomicSub(&cnt[d4.w], 1) - 1] = s4.w;
    }
}

// ====== Prep: x->fp16, W0..W2->fp16, zero sentinel rows (one kernel) ======
__global__ void prep_kernel(const float* __restrict__ x,
                            const float* __restrict__ W0,
                            const float* __restrict__ W1,
                            const float* __restrict__ W2,
                            __half* __restrict__ x16,
                            __half* __restrict__ w16,   // [3][4096]
                            __half* __restrict__ bufA,
                            __half* __restrict__ bufB) {
    int b = blockIdx.x;
    if (b < NB_CVT) {
        int i = b * 256 + threadIdx.x;
        float4 v = ((const float4*)x)[i];
        ((__half2*)x16)[2 * i + 0] = __floats2half2_rn(v.x, v.y);
        ((__half2*)x16)[2 * i + 1] = __floats2half2_rn(v.z, v.w);
    } else if (b < NB_CVT + 3) {
        int l = b - NB_CVT;
        const float* W = (l == 0) ? W0 : (l == 1) ? W1 : W2;
        for (int j = threadIdx.x; j < D * D; j += 256)
            w16[l * D * D + j] = __float2half(W[j]);
    } else {
        int tid = threadIdx.x;
        if (tid < 96) {
            __half* p = (tid < 32) ? x16 : (tid < 64) ? bufA : bufB;
            ((unsigned int*)(p + SENTINEL * D))[tid & 31] = 0u;
        }
    }
}

// ================= Gather: S[n] = h[n] + sum_neighbors h ==================
// (round-10 exact form; no nt — S is re-read by mlp immediately)
__global__ __launch_bounds__(256) void gather_kernel(
        const __half* __restrict__ h_in,
        const int* __restrict__ ofs,
        const int* __restrict__ esrc,
        __half* __restrict__ s_out) {
    int w = threadIdx.x >> 6, lane = threadIdx.x & 63;
    int q = lane >> 4;
    int c4 = lane & 15;
    int n = blockIdx.x * 16 + w * 4 + q;
    const uint2* hp = (const uint2*)h_in;

    uint2 self = hp[n * 16 + c4];
    float2 sl = __half22float2(*(const __half2*)&self.x);
    float2 sh = __half22float2(*(const __half2*)&self.y);
    float a0 = sl.x, a1 = sl.y, a2 = sh.x, a3 = sh.y;

    int k = ofs[n], end = ofs[n + 1];
    for (; k < end; k += 8) {
        int4 i0 = *(const int4*)(esrc + k);
        int4 i1 = *(const int4*)(esrc + k + 4);
        uint2 r0 = hp[i0.x * 16 + c4];
        uint2 r1 = hp[i0.y * 16 + c4];
        uint2 r2 = hp[i0.z * 16 + c4];
        uint2 r3 = hp[i0.w * 16 + c4];
        uint2 r4 = hp[i1.x * 16 + c4];
        uint2 r5 = hp[i1.y * 16 + c4];
        uint2 r6 = hp[i1.z * 16 + c4];
        uint2 r7 = hp[i1.w * 16 + c4];
#define ACC(R) { float2 lo = __half22float2(*(const __half2*)&R.x); \
                 float2 hi = __half22float2(*(const __half2*)&R.y); \
                 a0 += lo.x; a1 += lo.y; a2 += hi.x; a3 += hi.y; }
        ACC(r0) ACC(r1) ACC(r2) ACC(r3) ACC(r4) ACC(r5) ACC(r6) ACC(r7)
#undef ACC
    }
    uint2 ov;
    *(__half2*)&ov.x = __floats2half2_rn(a0, a1);
    *(__half2*)&ov.y = __floats2half2_rn(a2, a3);
    ((uint2*)s_out)[n * 16 + c4] = ov;
}

// ================= MLP: h' = relu(S @ W) via MFMA =========================
// (round-10 exact form)
__global__ __launch_bounds__(256) void mlp_kernel(
        const __half* __restrict__ S,
        const __half* __restrict__ W16,   // [64][64] fp16 [in][out]
        __half* __restrict__ h_out) {
    int w = threadIdx.x >> 6, lane = threadIdx.x & 63;
    int m = lane & 15;
    int kg = lane >> 4;
    const _Float16* Wp = (const _Float16*)W16;
    f16x8 bf[4][2];
#pragma unroll
    for (int ct = 0; ct < 4; ++ct)
#pragma unroll
        for (int kt = 0; kt < 2; ++kt)
#pragma unroll
            for (int j = 0; j < 8; ++j)
                bf[ct][kt][j] = Wp[(kt * 32 + kg * 8 + j) * D + ct * 16 + m];

    int t = blockIdx.x * 4 + w;
    if (t >= N_NODES / 16) return;
    const _Float16* Sp = (const _Float16*)S;
    int row = t * 16 + m;
    f16x8 a0 = *(const f16x8*)(Sp + row * D + kg * 8);
    f16x8 a1 = *(const f16x8*)(Sp + row * D + 32 + kg * 8);
    f32x4 c[4];
#pragma unroll
    for (int ct = 0; ct < 4; ++ct) {
        f32x4 z = {0.f, 0.f, 0.f, 0.f};
        z = __builtin_amdgcn_mfma_f32_16x16x32_f16(a0, bf[ct][0], z, 0, 0, 0);
        z = __builtin_amdgcn_mfma_f32_16x16x32_f16(a1, bf[ct][1], z, 0, 0, 0);
        c[ct] = z;
    }
#pragma unroll
    for (int ct = 0; ct < 4; ++ct)
#pragma unroll
        for (int r = 0; r < 4; ++r)
            h_out[(t * 16 + kg * 4 + r) * D + ct * 16 + m] =
                __float2half(fmaxf(c[ct][r], 0.f));
}

// ============ Final: L2-normalize + 64->16 linear (fp16 in) ===============
__global__ __launch_bounds__(256) void final_kernel(
        const __half* __restrict__ h,
        const float* __restrict__ W_out,
        const float* __restrict__ b_out,
        float* __restrict__ out,    // [N,16]
        float* __restrict__ feat) { // [N,64]
    __shared__ float Wo[D][N_CLASSES];
    __shared__ float fs[4][2][D];
    int tid = threadIdx.x;
    for (int k = tid; k < D * N_CLASSES; k += 256)
        Wo[k >> 4][k & 15] = W_out[k];
    __syncthreads();
    int w = tid >> 6;
    int lane = tid & 63;
    int hh = lane >> 5;
    int c2 = lane & 31;
    const __half2* hp = (const __half2*)h;
    float bias = b_out[lane & 15];

    for (int g = blockIdx.x; g < NG8; g += GRID) {
        int n = g * 8 + w * 2 + hh;
        float2 v = __half22float2(hp[n * 32 + c2]);
        float ss = v.x * v.x + v.y * v.y;
#pragma unroll
        for (int off = 16; off; off >>= 1)
            ss += __shfl_xor(ss, off);
        float rinv = 1.f / fmaxf(sqrtf(ss), 1e-12f);
        float f0 = v.x * rinv, f1 = v.y * rinv;
        ((float2*)feat)[n * 32 + c2] = make_float2(f0, f1);
        fs[w][hh][2 * c2 + 0] = f0;
        fs[w][hh][2 * c2 + 1] = f1;
        if (c2 < N_CLASSES) {
            float acc = bias;
#pragma unroll
            for (int i = 0; i < D; ++i)
                acc = fmaf(fs[w][hh][i], Wo[i][c2], acc);
            out[n * N_CLASSES + c2] = acc;
        }
    }
}

// ==========================================================================
extern "C" void kernel_launch(void* const* d_in, const int* in_sizes, int n_in,
                              void* d_out, int out_size, void* d_ws, size_t ws_size,
                              hipStream_t stream) {
    const float* x     = (const float*)d_in[0];
    const int*   src   = (const int*)d_in[1];
    const int*   dst   = (const int*)d_in[2];
    const float* W0    = (const float*)d_in[3];
    const float* W1    = (const float*)d_in[4];
    const float* W2    = (const float*)d_in[5];
    const float* W_out = (const float*)d_in[6];
    const float* b_out = (const float*)d_in[7];

    float* out  = (float*)d_out;
    float* feat = (float*)d_out + (size_t)N_NODES * N_CLASSES;

    const int NB_NODE = (N_NODES + 255) / 256;       // 391
    const int NB_MLP  = (N_NODES / 16 + 3) / 4;      // 1563
    const int NB_BKT  = (N_EDGES / 4 + 255) / 256;   // 1172

    // ws layout; h buffers have N_NODES+1 rows (sentinel zero row)
    size_t off = 0;
    auto alloc = [&](size_t bytes) { size_t o = off; off = (off + bytes + 255) & ~(size_t)255; return o; };
    size_t o_cnt     = alloc((size_t)N_NODES * 4);
    size_t o_partial = alloc(512 * 4);
    size_t o_ofs     = alloc(((size_t)N_NODES + 1) * 4);
    size_t o_esrc    = alloc((size_t)ESRC_CAP * 4);
    size_t o_w16     = alloc((size_t)3 * D * D * 2);
    size_t o_X       = alloc((size_t)(N_NODES + 1) * D * 2);
    size_t o_A       = alloc((size_t)(N_NODES + 1) * D * 2);
    size_t o_B       = alloc((size_t)(N_NODES + 1) * D * 2);
    size_t need_base = off;
    size_t o_bcur    = alloc(8 * 4);
    size_t o_bsrc    = alloc((size_t)8 * BCAP * 4);
    size_t o_bdst    = alloc((size_t)8 * BCAP * 4);
    size_t need_bkt  = off;

    char* w8 = (char*)d_ws;
    int*    cnt     = (int*)(w8 + o_cnt);
    int*    partial = (int*)(w8 + o_partial);
    int*    ofs     = (int*)(w8 + o_ofs);
    int*    esrc    = (int*)(w8 + o_esrc);
    __half* w16     = (__half*)(w8 + o_w16);
    __half* X       = (__half*)(w8 + o_X);
    __half* A       = (__half*)(w8 + o_A);
    __half* B       = (__half*)(w8 + o_B);

    hipMemsetAsync(cnt, 0, (size_t)N_NODES * 4, stream);

    if (ws_size >= need_bkt) {
        int* bcur = (int*)(w8 + o_bcur);
        int* bsrc = (int*)(w8 + o_bsrc);
        int* bdst = (int*)(w8 + o_bdst);
        hipMemsetAsync(bcur, 0, 8 * 4, stream);
        // bucket -> local hist -> scan -> scan_add -> local scatter
        bucket_kernel<<<NB_BKT, 256, 0, stream>>>(src, dst, bcur, bsrc, bdst);
        hist_bucket_kernel<<<GRID, 256, 0, stream>>>(bcur, bdst, cnt);
        scan_block_kernel<<<NB_NODE, 256, 0, stream>>>(cnt, ofs, partial);
        scan_partials_kernel<<<1, 512, 0, stream>>>(partial, NB_NODE);
        scan_add_kernel<<<NB_NODE, 256, 0, stream>>>(ofs, partial, cnt, esrc);
        scatter_bucket_kernel<<<GRID, 256, 0, stream>>>(bcur, bsrc, bdst, ofs, cnt, esrc);
    } else {
        hist_kernel<<<GRID, 256, 0, stream>>>(dst, cnt);
        scan_block_kernel<<<NB_NODE, 256, 0, stream>>>(cnt, ofs, partial);
        scan_partials_kernel<<<1, 512, 0, stream>>>(partial, NB_NODE);
        scan_add_kernel<<<NB_NODE, 256, 0, stream>>>(ofs, partial, cnt, esrc);
        scatter_edges_kernel<<<GRID, 256, 0, stream>>>(src, dst, ofs, cnt, esrc);
    }

    // --- prep: x->fp16, W->fp16, zero sentinel rows ---
    prep_kernel<<<NB_CVT + 4, 256, 0, stream>>>(x, W0, W1, W2, X, w16, A, B);

    // --- 3 layers: gather then MFMA MLP; buffers rotate X->A->B ---
    gather_kernel<<<N_NODES / 16, 256, 0, stream>>>(X, ofs, esrc, A);       // S1=A
    mlp_kernel<<<NB_MLP, 256, 0, stream>>>(A, w16 + 0 * D * D, B);          // h1=B
    gather_kernel<<<N_NODES / 16, 256, 0, stream>>>(B, ofs, esrc, X);       // S2=X
    mlp_kernel<<<NB_MLP, 256, 0, stream>>>(X, w16 + 1 * D * D, A);          // h2=A
    gather_kernel<<<N_NODES / 16, 256, 0, stream>>>(A, ofs, esrc, B);       // S3=B
    mlp_kernel<<<NB_MLP, 256, 0, stream>>>(B, w16 + 2 * D * D, X);          // h3=X

    final_kernel<<<GRID, 256, 0, stream>>>(X, W_out, b_out, out, feat);
}

// Round 13
// 192.265 us; speedup vs baseline: 1.5059x; 1.4239x over previous
//
#include <hip/hip_runtime.h>
#include <hip/hip_fp16.h>

#define N_NODES 100000
#define N_EDGES 1200000
#define D 64
#define N_CLASSES 16
#define NG8  (N_NODES / 8)
#define GRID 2048
#define NXCD 8
#define DRANGE ((N_NODES + NXCD - 1) / NXCD)
#define ESRC_CAP 1900032           // >= E + 7N (pad-8)
#define SENTINEL N_NODES           // index of the all-zero h row
#define NB_CVT 6250
// node-range counting sort
#define NRB 1024                   // node-range buckets
#define RW 98                      // nodes per bucket (1024*98 >= 100000)
#define RCAP 2048                  // per-bucket edge capacity (mean 1172, 25 sigma)
#define K1CH 1024                  // int4 chunks per K1 block (4096 edges)
#define K1B ((N_EDGES / 4 + K1CH - 1) / K1CH)   // 293

typedef _Float16 f16x8 __attribute__((ext_vector_type(8)));
typedef float    f32x4 __attribute__((ext_vector_type(4)));

// ============== K1: bin edges into 1024 node-range buckets ================
// LDS ranking + in-LDS counting sort; ~300K block-level cursor atomics total
// (vs 1.2M per-edge atomics previously). Packed edge: (src<<7)|(dst-base).
__global__ __launch_bounds__(256) void bucket_nr_kernel(
        const int* __restrict__ src,
        const int* __restrict__ dst,
        int* __restrict__ bcur,          // [NRB]
        int* __restrict__ bpk) {         // [NRB][RCAP]
    __shared__ int hist[NRB];
    __shared__ int lofs[NRB + 1];
    __shared__ int gbase[NRB];
    __shared__ int tsum[256];
    __shared__ int pk[K1CH * 4];         // 16KB
    int tid = threadIdx.x;
    for (int i = tid; i < NRB; i += 256) hist[i] = 0;
    __syncthreads();

    int c0 = blockIdx.x * K1CH;
    int bn_rk[4][4], pkv[4][4];
#pragma unroll
    for (int it = 0; it < 4; ++it) {
        int c = c0 + it * 256 + tid;
        if (c < N_EDGES / 4) {
            int4 s4 = ((const int4*)src)[c];
            int4 d4 = ((const int4*)dst)[c];
            int ss[4] = {s4.x, s4.y, s4.z, s4.w};
            int dd[4] = {d4.x, d4.y, d4.z, d4.w};
#pragma unroll
            for (int j = 0; j < 4; ++j) {
                int b = dd[j] / RW;
                int rk = atomicAdd(&hist[b], 1);
                bn_rk[it][j] = (b << 16) | rk;          // rk < 4096
                pkv[it][j] = (ss[j] << 7) | (dd[j] - b * RW);
            }
        } else {
#pragma unroll
            for (int j = 0; j < 4; ++j) bn_rk[it][j] = -1;
        }
    }
    __syncthreads();
    // block-wide exclusive scan of hist[1024] (4 entries/thread + ladder)
    int b4 = tid * 4;
    int h0 = hist[b4], h1 = hist[b4 + 1], h2 = hist[b4 + 2], h3 = hist[b4 + 3];
    int hs = h0 + h1 + h2 + h3;
    tsum[tid] = hs;
    __syncthreads();
    for (int d = 1; d < 256; d <<= 1) {
        int t = (tid >= d) ? tsum[tid - d] : 0;
        __syncthreads();
        tsum[tid] += t;
        __syncthreads();
    }
    int ex = tsum[tid] - hs;
    lofs[b4] = ex; lofs[b4 + 1] = ex + h0;
    lofs[b4 + 2] = ex + h0 + h1; lofs[b4 + 3] = ex + h0 + h1 + h2;
    if (tid == 255) lofs[NRB] = tsum[255];
    // global cursors (block-level, not per-edge)
    for (int b = tid; b < NRB; b += 256) {
        int cb = hist[b];
        gbase[b] = cb ? atomicAdd(&bcur[b], cb) : 0;
    }
    __syncthreads();
    // counting-sort into LDS
#pragma unroll
    for (int it = 0; it < 4; ++it)
#pragma unroll
        for (int j = 0; j < 4; ++j) {
            int br = bn_rk[it][j];
            if (br >= 0)
                pk[lofs[br >> 16] + (br & 0xffff)] = pkv[it][j];
        }
    __syncthreads();
    // coalesced flush (binary search for bucket of each position)
    int total = lofs[NRB];
    for (int i = tid; i < total; i += 256) {
        int lo = 0, hi = NRB;
        while (hi - lo > 1) {
            int mid = (lo + hi) >> 1;
            if (lofs[mid] <= i) lo = mid; else hi = mid;
        }
        int pos = gbase[lo] + (i - lofs[lo]);
        if (pos < RCAP) bpk[lo * RCAP + pos] = pk[i];
    }
}

// ============== K2: per-range histogram (plain stores, no memset) =========
__global__ __launch_bounds__(256) void hist_nr_kernel(
        const int* __restrict__ bcur,
        const int* __restrict__ bpk,
        int* __restrict__ cnt) {
    __shared__ int lh[RW];
    int r = blockIdx.x, tid = threadIdx.x;
    if (tid < RW) lh[tid] = 0;
    __syncthreads();
    int nb = min(bcur[r], RCAP);
    const int* p = bpk + r * RCAP;
    for (int i = tid; i < nb; i += 256)
        atomicAdd(&lh[p[i] & 127], 1);
    __syncthreads();
    int n = r * RW + tid;
    if (tid < RW && n < N_NODES) cnt[n] = lh[tid];
}

// Exclusive scan over PADDED degrees: pad_deg = ceil(deg/8)*8.
__global__ void scan_block_kernel(const int* __restrict__ cnt,
                                  int* __restrict__ ofs,
                                  int* __restrict__ partial) {
    __shared__ int s[256];
    int tid = threadIdx.x;
    int i = blockIdx.x * 256 + tid;
    int v = (i < N_NODES) ? ((cnt[i] + 7) & ~7) : 0;
    s[tid] = v;
    __syncthreads();
    for (int d = 1; d < 256; d <<= 1) {
        int t = (tid >= d) ? s[tid - d] : 0;
        __syncthreads();
        s[tid] += t;
        __syncthreads();
    }
    if (i < N_NODES) ofs[i] = s[tid] - v;
    if (tid == 255) partial[blockIdx.x] = s[255];
}

__global__ void scan_partials_kernel(int* __restrict__ partial, int nb) {
    __shared__ int s[512];
    int tid = threadIdx.x;
    int v = (tid < nb) ? partial[tid] : 0;
    s[tid] = v;
    __syncthreads();
    for (int d = 1; d < 512; d <<= 1) {
        int t = (tid >= d) ? s[tid - d] : 0;
        __syncthreads();
        s[tid] += t;
        __syncthreads();
    }
    if (tid < nb) partial[tid] = s[tid] - v;
}

// Adds block prefix AND writes the <=7 sentinel pads of each node's segment.
__global__ void scan_add_kernel(int* __restrict__ ofs,
                                const int* __restrict__ partial,
                                const int* __restrict__ cnt,
                                int* __restrict__ esrc) {
    int i = blockIdx.x * 256 + threadIdx.x;
    if (i < N_NODES) {
        int o = ofs[i] + partial[blockIdx.x];
        ofs[i] = o;
        int c = cnt[i], p = (c + 7) & ~7;
        for (int j = c; j < p; ++j) esrc[o + j] = SENTINEL;
        if (i == N_NODES - 1) ofs[N_NODES] = o + p;
    }
}

// ============== K5: place edges (LDS cursors, plain stores) ===============
__global__ __launch_bounds__(256) void place_nr_kernel(
        const int* __restrict__ bcur,
        const int* __restrict__ bpk,
        const int* __restrict__ ofs,
        int* __restrict__ esrc) {
    __shared__ int lof[RW];
    __shared__ int lcur[RW];
    int r = blockIdx.x, tid = threadIdx.x;
    int n = r * RW + tid;
    if (tid < RW) {
        lof[tid] = (n < N_NODES) ? ofs[n] : 0;
        lcur[tid] = 0;
    }
    __syncthreads();
    int nb = min(bcur[r], RCAP);
    const int* p = bpk + r * RCAP;
    for (int i = tid; i < nb; i += 256) {
        int v = p[i];
        int dl = v & 127;
        int rk = atomicAdd(&lcur[dl], 1);
        esrc[lof[dl] + rk] = (unsigned)v >> 7;
    }
}

// --- Fallback CSR (round-10 path, if ws too small) ------------------------
__global__ __launch_bounds__(256) void hist_kernel(const int* __restrict__ dst,
                                                   int* __restrict__ cnt) {
    int g = blockIdx.x & (NXCD - 1);
    int lo = g * DRANGE, hi = lo + DRANGE;
    int t = (blockIdx.x >> 3) * 256 + threadIdx.x;
    const int NCH = N_EDGES / 4;
    const int STRIDE = (GRID / NXCD) * 256;
    for (int c = t; c < NCH; c += STRIDE) {
        int4 d4 = ((const int4*)dst)[c];
        if (d4.x >= lo && d4.x < hi) atomicAdd(&cnt[d4.x], 1);
        if (d4.y >= lo && d4.y < hi) atomicAdd(&cnt[d4.y], 1);
        if (d4.z >= lo && d4.z < hi) atomicAdd(&cnt[d4.z], 1);
        if (d4.w >= lo && d4.w < hi) atomicAdd(&cnt[d4.w], 1);
    }
}

__global__ __launch_bounds__(256) void scatter_edges_kernel(
        const int* __restrict__ src,
        const int* __restrict__ dst,
        const int* __restrict__ ofs,
        int* __restrict__ cnt,
        int* __restrict__ esrc) {
    int g = blockIdx.x & (NXCD - 1);
    int lo = g * DRANGE, hi = lo + DRANGE;
    int t = (blockIdx.x >> 3) * 256 + threadIdx.x;
    const int NCH = N_EDGES / 4;
    const int STRIDE = (GRID / NXCD) * 256;
    for (int c = t; c < NCH; c += STRIDE) {
        int4 s4 = ((const int4*)src)[c];
        int4 d4 = ((const int4*)dst)[c];
        if (d4.x >= lo && d4.x < hi) esrc[ofs[d4.x] + atomicSub(&cnt[d4.x], 1) - 1] = s4.x;
        if (d4.y >= lo && d4.y < hi) esrc[ofs[d4.y] + atomicSub(&cnt[d4.y], 1) - 1] = s4.y;
        if (d4.z >= lo && d4.z < hi) esrc[ofs[d4.z] + atomicSub(&cnt[d4.z], 1) - 1] = s4.z;
        if (d4.w >= lo && d4.w < hi) esrc[ofs[d4.w] + atomicSub(&cnt[d4.w], 1) - 1] = s4.w;
    }
}

// ====== Prep: x->fp16, W0..W2->fp16, zero sentinel rows (one kernel) ======
__global__ void prep_kernel(const float* __restrict__ x,
                            const float* __restrict__ W0,
                            const float* __restrict__ W1,
                            const float* __restrict__ W2,
                            __half* __restrict__ x16,
                            __half* __restrict__ w16,
                            __half* __restrict__ bufA,
                            __half* __restrict__ bufB) {
    int b = blockIdx.x;
    if (b < NB_CVT) {
        int i = b * 256 + threadIdx.x;
        float4 v = ((const float4*)x)[i];
        ((__half2*)x16)[2 * i + 0] = __floats2half2_rn(v.x, v.y);
        ((__half2*)x16)[2 * i + 1] = __floats2half2_rn(v.z, v.w);
    } else if (b < NB_CVT + 3) {
        int l = b - NB_CVT;
        const float* W = (l == 0) ? W0 : (l == 1) ? W1 : W2;
        for (int j = threadIdx.x; j < D * D; j += 256)
            w16[l * D * D + j] = __float2half(W[j]);
    } else {
        int tid = threadIdx.x;
        if (tid < 96) {
            __half* p = (tid < 32) ? x16 : (tid < 64) ? bufA : bufB;
            ((unsigned int*)(p + SENTINEL * D))[tid & 31] = 0u;
        }
    }
}

// ================= Gather: S[n] = h[n] + sum_neighbors h ==================
__global__ __launch_bounds__(256) void gather_kernel(
        const __half* __restrict__ h_in,
        const int* __restrict__ ofs,
        const int* __restrict__ esrc,
        __half* __restrict__ s_out) {
    int w = threadIdx.x >> 6, lane = threadIdx.x & 63;
    int q = lane >> 4;
    int c4 = lane & 15;
    int n = blockIdx.x * 16 + w * 4 + q;
    const uint2* hp = (const uint2*)h_in;

    uint2 self = hp[n * 16 + c4];
    float2 sl = __half22float2(*(const __half2*)&self.x);
    float2 sh = __half22float2(*(const __half2*)&self.y);
    float a0 = sl.x, a1 = sl.y, a2 = sh.x, a3 = sh.y;

    int k = ofs[n], end = ofs[n + 1];
    for (; k < end; k += 8) {
        int4 i0 = *(const int4*)(esrc + k);
        int4 i1 = *(const int4*)(esrc + k + 4);
        uint2 r0 = hp[i0.x * 16 + c4];
        uint2 r1 = hp[i0.y * 16 + c4];
        uint2 r2 = hp[i0.z * 16 + c4];
        uint2 r3 = hp[i0.w * 16 + c4];
        uint2 r4 = hp[i1.x * 16 + c4];
        uint2 r5 = hp[i1.y * 16 + c4];
        uint2 r6 = hp[i1.z * 16 + c4];
        uint2 r7 = hp[i1.w * 16 + c4];
#define ACC(R) { float2 lo = __half22float2(*(const __half2*)&R.x); \
                 float2 hi = __half22float2(*(const __half2*)&R.y); \
                 a0 += lo.x; a1 += lo.y; a2 += hi.x; a3 += hi.y; }
        ACC(r0) ACC(r1) ACC(r2) ACC(r3) ACC(r4) ACC(r5) ACC(r6) ACC(r7)
#undef ACC
    }
    uint2 ov;
    *(__half2*)&ov.x = __floats2half2_rn(a0, a1);
    *(__half2*)&ov.y = __floats2half2_rn(a2, a3);
    ((uint2*)s_out)[n * 16 + c4] = ov;
}

// ================= MLP: h' = relu(S @ W) via MFMA =========================
__global__ __launch_bounds__(256) void mlp_kernel(
        const __half* __restrict__ S,
        const __half* __restrict__ W16,
        __half* __restrict__ h_out) {
    int w = threadIdx.x >> 6, lane = threadIdx.x & 63;
    int m = lane & 15;
    int kg = lane >> 4;
    const _Float16* Wp = (const _Float16*)W16;
    f16x8 bf[4][2];
#pragma unroll
    for (int ct = 0; ct < 4; ++ct)
#pragma unroll
        for (int kt = 0; kt < 2; ++kt)
#pragma unroll
            for (int j = 0; j < 8; ++j)
                bf[ct][kt][j] = Wp[(kt * 32 + kg * 8 + j) * D + ct * 16 + m];

    int t = blockIdx.x * 4 + w;
    if (t >= N_NODES / 16) return;
    const _Float16* Sp = (const _Float16*)S;
    int row = t * 16 + m;
    f16x8 a0 = *(const f16x8*)(Sp + row * D + kg * 8);
    f16x8 a1 = *(const f16x8*)(Sp + row * D + 32 + kg * 8);
    f32x4 c[4];
#pragma unroll
    for (int ct = 0; ct < 4; ++ct) {
        f32x4 z = {0.f, 0.f, 0.f, 0.f};
        z = __builtin_amdgcn_mfma_f32_16x16x32_f16(a0, bf[ct][0], z, 0, 0, 0);
        z = __builtin_amdgcn_mfma_f32_16x16x32_f16(a1, bf[ct][1], z, 0, 0, 0);
        c[ct] = z;
    }
#pragma unroll
    for (int ct = 0; ct < 4; ++ct)
#pragma unroll
        for (int r = 0; r < 4; ++r)
            h_out[(t * 16 + kg * 4 + r) * D + ct * 16 + m] =
                __float2half(fmaxf(c[ct][r], 0.f));
}

// ============ Final: L2-normalize + 64->16 linear (fp16 in) ===============
__global__ __launch_bounds__(256) void final_kernel(
        const __half* __restrict__ h,
        const float* __restrict__ W_out,
        const float* __restrict__ b_out,
        float* __restrict__ out,
        float* __restrict__ feat) {
    __shared__ float Wo[D][N_CLASSES];
    __shared__ float fs[4][2][D];
    int tid = threadIdx.x;
    for (int k = tid; k < D * N_CLASSES; k += 256)
        Wo[k >> 4][k & 15] = W_out[k];
    __syncthreads();
    int w = tid >> 6;
    int lane = tid & 63;
    int hh = lane >> 5;
    int c2 = lane & 31;
    const __half2* hp = (const __half2*)h;
    float bias = b_out[lane & 15];

    for (int g = blockIdx.x; g < NG8; g += GRID) {
        int n = g * 8 + w * 2 + hh;
        float2 v = __half22float2(hp[n * 32 + c2]);
        float ss = v.x * v.x + v.y * v.y;
#pragma unroll
        for (int off = 16; off; off >>= 1)
            ss += __shfl_xor(ss, off);
        float rinv = 1.f / fmaxf(sqrtf(ss), 1e-12f);
        float f0 = v.x * rinv, f1 = v.y * rinv;
        ((float2*)feat)[n * 32 + c2] = make_float2(f0, f1);
        fs[w][hh][2 * c2 + 0] = f0;
        fs[w][hh][2 * c2 + 1] = f1;
        if (c2 < N_CLASSES) {
            float acc = bias;
#pragma unroll
            for (int i = 0; i < D; ++i)
                acc = fmaf(fs[w][hh][i], Wo[i][c2], acc);
            out[n * N_CLASSES + c2] = acc;
        }
    }
}

// ==========================================================================
extern "C" void kernel_launch(void* const* d_in, const int* in_sizes, int n_in,
                              void* d_out, int out_size, void* d_ws, size_t ws_size,
                              hipStream_t stream) {
    const float* x     = (const float*)d_in[0];
    const int*   src   = (const int*)d_in[1];
    const int*   dst   = (const int*)d_in[2];
    const float* W0    = (const float*)d_in[3];
    const float* W1    = (const float*)d_in[4];
    const float* W2    = (const float*)d_in[5];
    const float* W_out = (const float*)d_in[6];
    const float* b_out = (const float*)d_in[7];

    float* out  = (float*)d_out;
    float* feat = (float*)d_out + (size_t)N_NODES * N_CLASSES;

    const int NB_NODE = (N_NODES + 255) / 256;       // 391
    const int NB_MLP  = (N_NODES / 16 + 3) / 4;      // 1563

    size_t off = 0;
    auto alloc = [&](size_t bytes) { size_t o = off; off = (off + bytes + 255) & ~(size_t)255; return o; };
    size_t o_cnt     = alloc((size_t)N_NODES * 4);
    size_t o_partial = alloc(512 * 4);
    size_t o_ofs     = alloc(((size_t)N_NODES + 1) * 4);
    size_t o_esrc    = alloc((size_t)ESRC_CAP * 4);
    size_t o_w16     = alloc((size_t)3 * D * D * 2);
    size_t o_X       = alloc((size_t)(N_NODES + 1) * D * 2);
    size_t o_A       = alloc((size_t)(N_NODES + 1) * D * 2);
    size_t o_B       = alloc((size_t)(N_NODES + 1) * D * 2);
    size_t o_bcur    = alloc((size_t)NRB * 4);
    size_t o_bpk     = alloc((size_t)NRB * RCAP * 4);    // 8.4MB
    size_t need_bkt  = off;

    char* w8 = (char*)d_ws;
    int*    cnt     = (int*)(w8 + o_cnt);
    int*    partial = (int*)(w8 + o_partial);
    int*    ofs     = (int*)(w8 + o_ofs);
    int*    esrc    = (int*)(w8 + o_esrc);
    __half* w16     = (__half*)(w8 + o_w16);
    __half* X       = (__half*)(w8 + o_X);
    __half* A       = (__half*)(w8 + o_A);
    __half* B       = (__half*)(w8 + o_B);

    if (ws_size >= need_bkt) {
        int* bcur = (int*)(w8 + o_bcur);
        int* bpk  = (int*)(w8 + o_bpk);
        hipMemsetAsync(bcur, 0, (size_t)NRB * 4, stream);
        bucket_nr_kernel<<<K1B, 256, 0, stream>>>(src, dst, bcur, bpk);
        hist_nr_kernel<<<NRB, 256, 0, stream>>>(bcur, bpk, cnt);
        scan_block_kernel<<<NB_NODE, 256, 0, stream>>>(cnt, ofs, partial);
        scan_partials_kernel<<<1, 512, 0, stream>>>(partial, NB_NODE);
        scan_add_kernel<<<NB_NODE, 256, 0, stream>>>(ofs, partial, cnt, esrc);
        place_nr_kernel<<<NRB, 256, 0, stream>>>(bcur, bpk, ofs, esrc);
    } else {
        hipMemsetAsync(cnt, 0, (size_t)N_NODES * 4, stream);
        hist_kernel<<<GRID, 256, 0, stream>>>(dst, cnt);
        scan_block_kernel<<<NB_NODE, 256, 0, stream>>>(cnt, ofs, partial);
        scan_partials_kernel<<<1, 512, 0, stream>>>(partial, NB_NODE);
        scan_add_kernel<<<NB_NODE, 256, 0, stream>>>(ofs, partial, cnt, esrc);
        scatter_edges_kernel<<<GRID, 256, 0, stream>>>(src, dst, ofs, cnt, esrc);
    }

    prep_kernel<<<NB_CVT + 4, 256, 0, stream>>>(x, W0, W1, W2, X, w16, A, B);

    gather_kernel<<<N_NODES / 16, 256, 0, stream>>>(X, ofs, esrc, A);
    mlp_kernel<<<NB_MLP, 256, 0, stream>>>(A, w16 + 0 * D * D, B);
    gather_kernel<<<N_NODES / 16, 256, 0, stream>>>(B, ofs, esrc, X);
    mlp_kernel<<<NB_MLP, 256, 0, stream>>>(X, w16 + 1 * D * D, A);
    gather_kernel<<<N_NODES / 16, 256, 0, stream>>>(A, ofs, esrc, B);
    mlp_kernel<<<NB_MLP, 256, 0, stream>>>(B, w16 + 2 * D * D, X);

    final_kernel<<<GRID, 256, 0, stream>>>(X, W_out, b_out, out, feat);
}